// Round 1
// baseline (26.389 us; speedup 1.0000x reference)
//
#include <hip/hip_runtime.h>

// KAN edge function:
//   out = w_base * silu(x) + w_spline * sum_b basis_b(x) * c_b
// Uniform cubic B-spline, GRID_SIZE=8, DEGREE=3 -> 11 bases, knots
// knots[k] = -8.75 + 1.25*k, k = 0..14 (15 knots, 14 deg-0 intervals).
// For x in [knots[j], knots[j+1]) (j = 0..13), nonzero bases are j-3..j with
// uniform cubic blending weights in t = (x - knots[j])/h:
//   B0=(1-t)^3/6, B1=(3t^3-6t^2+4)/6, B2=(-3t^3+3t^2+3t+1)/6, B3=t^3/6
// spline = c[j-3]*B0 + c[j-2]*B1 + c[j-1]*B2 + c[j]*B3  (out-of-range c = 0)
// Collapsed per interval j into cubic poly a + b t + c t^2 + d t^3.

constexpr int NUM_BASIS = 11;
constexpr int NUM_INTERVALS = 14;

__global__ __launch_bounds__(256) void kan_edge_kernel(
    const float* __restrict__ x,
    const float* __restrict__ w_base_p,
    const float* __restrict__ w_spline_p,
    const float* __restrict__ coeffs,
    float* __restrict__ out,
    int n4, int total)
{
    __shared__ float4 poly[NUM_INTERVALS];

    int tid = threadIdx.x;
    if (tid < NUM_INTERVALS) {
        // padded coeffs: cp[k] = coeffs[k-3] for k in [3,13] else 0
        // spline over interval j uses cp[j], cp[j+1], cp[j+2], cp[j+3]
        int j = tid;
        float c0 = (j - 3 >= 0 && j - 3 < NUM_BASIS) ? coeffs[j - 3] : 0.f; // cp[j]
        float c1 = (j - 2 >= 0 && j - 2 < NUM_BASIS) ? coeffs[j - 2] : 0.f; // cp[j+1]
        float c2 = (j - 1 >= 0 && j - 1 < NUM_BASIS) ? coeffs[j - 1] : 0.f; // cp[j+2]
        float c3 = (j     >= 0 && j     < NUM_BASIS) ? coeffs[j]     : 0.f; // cp[j+3]
        float a  = (c0 + 4.f * c1 + c2) * (1.f / 6.f);
        float b  = (c2 - c0) * 0.5f;
        float cc = (c0 - 2.f * c1 + c2) * 0.5f;
        float dd = (3.f * (c1 - c2) + (c3 - c0)) * (1.f / 6.f);
        poly[j] = make_float4(a, b, cc, dd);
    }
    __syncthreads();

    const float wb = w_base_p[0];
    const float ws = w_spline_p[0];

    const float4* __restrict__ x4 = (const float4*)x;
    float4* __restrict__ o4 = (float4*)out;

    int idx = blockIdx.x * blockDim.x + threadIdx.x;
    int stride = gridDim.x * blockDim.x;

    for (int i = idx; i < n4; i += stride) {
        float4 v = x4[i];
        float xs[4] = {v.x, v.y, v.z, v.w};
        float r[4];
#pragma unroll
        for (int k = 0; k < 4; ++k) {
            float xv = xs[k];
            // silu
            float sig = 1.f / (1.f + __expf(-xv));
            float base = xv * sig;
            // spline: interval index + local param
            float u = (xv + 8.75f) * 0.8f;   // (x - knot0) / h
            float jf = floorf(u);
            float t = u - jf;
            int j = (int)jf;
            float sp = 0.f;
            if (j >= 0 && j < NUM_INTERVALS) {
                float4 p = poly[j];
                sp = fmaf(fmaf(fmaf(p.w, t, p.z), t, p.y), t, p.x);
            }
            r[k] = fmaf(wb, base, ws * sp);
        }
        o4[i] = make_float4(r[0], r[1], r[2], r[3]);
    }

    // scalar tail (total not divisible by 4) — handled by first threads
    int tail_start = n4 * 4;
    for (int i = tail_start + idx; i < total; i += stride) {
        float xv = x[i];
        float sig = 1.f / (1.f + __expf(-xv));
        float base = xv * sig;
        float u = (xv + 8.75f) * 0.8f;
        float jf = floorf(u);
        float t = u - jf;
        int j = (int)jf;
        float sp = 0.f;
        if (j >= 0 && j < NUM_INTERVALS) {
            float4 p = poly[j];
            sp = fmaf(fmaf(fmaf(p.w, t, p.z), t, p.y), t, p.x);
        }
        out[i] = fmaf(wb, base, ws * sp);
    }
}

extern "C" void kernel_launch(void* const* d_in, const int* in_sizes, int n_in,
                              void* d_out, int out_size, void* d_ws, size_t ws_size,
                              hipStream_t stream) {
    const float* x        = (const float*)d_in[0];
    const float* w_base   = (const float*)d_in[1];
    const float* w_spline = (const float*)d_in[2];
    const float* coeffs   = (const float*)d_in[3];
    float* out = (float*)d_out;

    int total = out_size;           // 8192 * 2048
    int n4 = total / 4;

    int block = 256;
    int grid = (n4 + block - 1) / block;
    if (grid > 2048) grid = 2048;   // grid-stride the rest

    kan_edge_kernel<<<grid, block, 0, stream>>>(x, w_base, w_spline, coeffs,
                                                out, n4, total);
}